// Round 5
// baseline (421.580 us; speedup 1.0000x reference)
//
#include <hip/hip_runtime.h>
#include <math.h>

#define NN 64
#define CC 160
#define LL 4096
#define DD 160
#define MM 6
#define NCH 16   // chunks per image; each chunk = 256 tokens = 4 tiles of 64
#define NT 4

__device__ __forceinline__ float bf2f(unsigned short u) {
  union { unsigned int i; float f; } v; v.i = ((unsigned int)u) << 16; return v.f;
}
__device__ __forceinline__ unsigned short f2bf(float f) {
  union { float f; unsigned int i; } v; v.f = f;
  unsigned int r = v.i + 0x7fffu + ((v.i >> 16) & 1u);
  return (unsigned short)(r >> 16);
}
__device__ __forceinline__ float u2f_lo(unsigned int w) {
  union { unsigned int i; float f; } v; v.i = w << 16; return v.f;
}
__device__ __forceinline__ float u2f_hi(unsigned int w) {
  union { unsigned int i; float f; } v; v.i = w & 0xffff0000u; return v.f;
}

// ---------------- k_init: scal = (d^-0.5 / tau); Wkq1 = scal * Wk @ q1^T ----------------
__global__ __launch_bounds__(256) void k_init(
    const float* log_tau, const float* slots_init, const float* q_g, const float* q_b,
    const float* Wq, const float* Wk, float* Wkq1, float* scal) {
  __shared__ float ln[MM * DD];
  __shared__ float qv[MM * DD];
  __shared__ float mu_s[MM], rs_s[MM];
  int tid = threadIdx.x;
  float x = log_tau[0];
  float sp = (x > 20.f) ? x : log1pf(expf(x));
  float scv = (1.0f / sqrtf((float)DD)) / (sp + 0.5f);
  if (blockIdx.x == 0 && tid == 0) scal[0] = scv;
  if (tid < MM) {
    float s = 0.f, ss = 0.f;
    for (int i = 0; i < DD; i++) { float v = slots_init[tid * DD + i]; s += v; ss += v * v; }
    float mu = s / DD, var = ss / DD - mu * mu;
    mu_s[tid] = mu; rs_s[tid] = rsqrtf(var + 1e-5f);
  }
  __syncthreads();
  for (int o = tid; o < MM * DD; o += 256) {
    int m = o / DD, d = o % DD;
    ln[o] = (slots_init[o] - mu_s[m]) * rs_s[m] * q_g[d] + q_b[d];
  }
  __syncthreads();
  for (int o = tid; o < MM * DD; o += 256) {
    int m = o / DD, d = o % DD;
    float acc = 0.f;
#pragma unroll 8
    for (int i = 0; i < DD; i++) acc += ln[m * DD + i] * Wq[i * DD + d];
    qv[o] = acc;
  }
  __syncthreads();
  for (int o = tid; o < 60; o += 256) {
    int c = blockIdx.x * 10 + o / 6, m = o % 6;
    float acc = 0.f;
#pragma unroll 8
    for (int d = 0; d < DD; d++) acc += Wk[c * DD + d] * qv[m * DD + d];
    Wkq1[c * 6 + m] = scv * acc;
  }
}

// ---------------- k_init2: P1 = g .* Wkq1; ab = [alpha | beta] ----------------
__global__ __launch_bounds__(256) void k_init2(
    const float* Wkq1, const float* kv_g, const float* kv_b, float* P1, float* ab) {
  int tid = threadIdx.x;
  for (int o = tid; o < DD * 6; o += 256) {
    int c = o / 6;
    P1[o] = kv_g[c] * Wkq1[o];
  }
  __syncthreads();
  if (tid < 12) {
    int m = tid % 6;
    float s = 0.f;
    if (tid < 6) { for (int c = 0; c < DD; c++) s += P1[c * 6 + m]; }
    else         { for (int c = 0; c < DD; c++) s += kv_b[c] * Wkq1[c * 6 + m]; }
    ab[tid] = s;
  }
}

// ---------------- k_pass1: pipelined fused {LN+logits} -> softmax -> A-accum + xcache ----------------
__global__ __launch_bounds__(256, 3) void k_pass1(
    const float* __restrict__ feat, const float* __restrict__ kv_g, const float* __restrict__ kv_b,
    const float* __restrict__ P1, const float* __restrict__ ab,
    unsigned short* __restrict__ xcache, float* __restrict__ Apart, float* __restrict__ Spart) {
  int b = blockIdx.x;
  int n = b >> 4, ch = b & 15;
  int tid = threadIdx.x;
  int lane = tid & 63, g = tid >> 6;
  __shared__ __align__(16) unsigned short xln[64][168];  // 336B rows (16B-mult)
  __shared__ float part[4][64][9];
  __shared__ __align__(16) float att[64][8];
  __shared__ __align__(16) float P_s[160][8];
  __shared__ float kvg_s[160], kvb_s[160];
  __shared__ float sred[64][6];

  const float* fbase = feat + ((size_t)(n * CC + g * 40)) * LL + ch * (64 * NT) + lane;
  float rvA[40], rvB[40];
  // issue tile-0 loads first (overlap with LDS preload)
#pragma unroll
  for (int i = 0; i < 40; i++) rvA[i] = fbase[(size_t)i * LL];

  for (int o = tid; o < DD; o += 256) { kvg_s[o] = kv_g[o]; kvb_s[o] = kv_b[o]; }
  for (int o = tid; o < DD * 6; o += 256) P_s[o / 6][o % 6] = P1[o];
  float alpha[6], beta[6];
#pragma unroll
  for (int m = 0; m < 6; m++) { alpha[m] = ab[m]; beta[m] = ab[6 + m]; }
  float Aacc[6] = {0, 0, 0, 0, 0, 0};
  float Sacc[6] = {0, 0, 0, 0, 0, 0};
  __syncthreads();

#define BODY1(RV, NRV, T, HASNEXT)                                                   \
  {                                                                                  \
    if (HASNEXT) {                                                                   \
      _Pragma("unroll") for (int i = 0; i < 40; i++)                                 \
          NRV[i] = fbase[(size_t)i * LL + ((T) + 1) * 64];                           \
    }                                                                                \
    float s_ = 0.f, ss_ = 0.f;                                                       \
    float l0 = 0.f, l1 = 0.f, l2 = 0.f, l3 = 0.f, l4 = 0.f, l5 = 0.f;                \
    _Pragma("unroll") for (int i = 0; i < 40; i++) {                                 \
      float x_ = RV[i];                                                              \
      s_ += x_; ss_ = fmaf(x_, x_, ss_);                                             \
      float4 p03 = *(const float4*)&P_s[g * 40 + i][0];                              \
      float2 p45 = *(const float2*)&P_s[g * 40 + i][4];                              \
      l0 = fmaf(x_, p03.x, l0); l1 = fmaf(x_, p03.y, l1);                            \
      l2 = fmaf(x_, p03.z, l2); l3 = fmaf(x_, p03.w, l3);                            \
      l4 = fmaf(x_, p45.x, l4); l5 = fmaf(x_, p45.y, l5);                            \
    }                                                                                \
    part[g][lane][0] = s_;  part[g][lane][1] = ss_;                                  \
    part[g][lane][2] = l0;  part[g][lane][3] = l1;                                   \
    part[g][lane][4] = l2;  part[g][lane][5] = l3;                                   \
    part[g][lane][6] = l4;  part[g][lane][7] = l5;                                   \
    __syncthreads();                                                                 \
    float S_ = 0.f, SS_ = 0.f, L_[6] = {0, 0, 0, 0, 0, 0};                           \
    _Pragma("unroll") for (int gg = 0; gg < 4; gg++) {                               \
      S_ += part[gg][lane][0]; SS_ += part[gg][lane][1];                             \
      _Pragma("unroll") for (int m = 0; m < 6; m++) L_[m] += part[gg][lane][2 + m];  \
    }                                                                                \
    float mu_ = S_ * (1.0f / CC);                                                    \
    float var_ = SS_ * (1.0f / CC) - mu_ * mu_;                                      \
    float rs_ = rsqrtf(var_ + 1e-5f);                                                \
    if (tid < 64) {                                                                  \
      float lg_[6], mx_;                                                             \
      _Pragma("unroll") for (int m = 0; m < 6; m++)                                  \
          lg_[m] = rs_ * L_[m] - rs_ * mu_ * alpha[m] + beta[m];                     \
      mx_ = lg_[0];                                                                  \
      _Pragma("unroll") for (int m = 1; m < 6; m++) mx_ = fmaxf(mx_, lg_[m]);        \
      float e_[6], sum_ = 0.f;                                                       \
      _Pragma("unroll") for (int m = 0; m < 6; m++) {                                \
        e_[m] = __expf(lg_[m] - mx_); sum_ += e_[m];                                 \
      }                                                                              \
      float inv_ = 1.0f / sum_;                                                      \
      float a0 = e_[0] * inv_, a1 = e_[1] * inv_, a2 = e_[2] * inv_;                 \
      float a3 = e_[3] * inv_, a4 = e_[4] * inv_, a5 = e_[5] * inv_;                 \
      *(float4*)&att[lane][0] = make_float4(a0, a1, a2, a3);                         \
      *(float2*)&att[lane][4] = make_float2(a4, a5);                                 \
      Sacc[0] += a0; Sacc[1] += a1; Sacc[2] += a2;                                   \
      Sacc[3] += a3; Sacc[4] += a4; Sacc[5] += a5;                                   \
    }                                                                                \
    _Pragma("unroll") for (int q5 = 0; q5 < 5; q5++) {                               \
      unsigned short pk[8];                                                          \
      _Pragma("unroll") for (int j = 0; j < 8; j++) {                                \
        int c_ = g * 40 + q5 * 8 + j;                                                \
        float v_ = (RV[q5 * 8 + j] - mu_) * rs_ * kvg_s[c_] + kvb_s[c_];             \
        pk[j] = f2bf(v_);                                                            \
      }                                                                              \
      *(uint4*)&xln[lane][g * 40 + q5 * 8] = *(const uint4*)pk;                      \
    }                                                                                \
    __syncthreads();                                                                 \
    if (tid < DD) {                                                                  \
      _Pragma("unroll") for (int t_ = 0; t_ < 64; t_++) {                            \
        float xv = bf2f(xln[t_][tid]);                                               \
        float4 a03 = *(const float4*)&att[t_][0];                                    \
        float2 a45 = *(const float2*)&att[t_][4];                                    \
        Aacc[0] = fmaf(a03.x, xv, Aacc[0]); Aacc[1] = fmaf(a03.y, xv, Aacc[1]);      \
        Aacc[2] = fmaf(a03.z, xv, Aacc[2]); Aacc[3] = fmaf(a03.w, xv, Aacc[3]);      \
        Aacc[4] = fmaf(a45.x, xv, Aacc[4]); Aacc[5] = fmaf(a45.y, xv, Aacc[5]);      \
      }                                                                              \
    } else {                                                                         \
      unsigned short* dst = xcache + ((size_t)(n * LL + ch * (64 * NT) + (T) * 64)) * DD; \
      for (int i2 = tid - 160; i2 < 64 * 20; i2 += 96) {                             \
        int row = i2 / 20, c8 = i2 % 20;                                             \
        *(uint4*)(dst + (size_t)row * DD + c8 * 8) = *(const uint4*)&xln[row][c8 * 8]; \
      }                                                                              \
    }                                                                                \
    __syncthreads();                                                                 \
  }

  BODY1(rvA, rvB, 0, true);
  BODY1(rvB, rvA, 1, true);
  BODY1(rvA, rvB, 2, true);
  BODY1(rvB, rvA, 3, false);
#undef BODY1

  if (tid < DD) {
#pragma unroll
    for (int m = 0; m < 6; m++) Apart[((size_t)b * 6 + m) * DD + tid] = Aacc[m];
  }
  if (tid < 64) {
#pragma unroll
    for (int m = 0; m < 6; m++) sred[tid][m] = Sacc[m];
  }
  __syncthreads();
  if (tid < 6) {
    float s = 0.f;
    for (int t = 0; t < 64; t++) s += sred[t][tid];
    Spart[b * 6 + tid] = s;
  }
}

// ---------------- k_pass2: pipelined xcache read; 4-thr/token logits; accum; attn write ----------------
__global__ __launch_bounds__(256) void k_pass2(
    const unsigned short* __restrict__ xcache, const float* __restrict__ Wkq2,
    float* __restrict__ Apart, float* __restrict__ Spart, float* __restrict__ attn_out) {
  int b = blockIdx.x;
  int n = b >> 4, ch = b & 15;
  int tid = threadIdx.x;
  __shared__ __align__(16) unsigned short xln[64][168];
  __shared__ float wkq_s[160][10];   // row stride 40B: kills same-bank across q
  __shared__ __align__(16) float att[64][8];
  __shared__ float sred[64][6];

  const unsigned short* src0 = xcache + ((size_t)(n * LL + ch * (64 * NT))) * DD;
  uint4 pf[5];
  // prologue: load tile 0
#pragma unroll
  for (int k = 0; k < 5; k++) {
    int i = tid + k * 256, row = i / 20, c8 = i % 20;
    pf[k] = *(const uint4*)(src0 + (size_t)row * DD + c8 * 8);
  }
  const float* wsrc = Wkq2 + (size_t)n * DD * 6;
  for (int o = tid; o < DD * 6; o += 256) wkq_s[o / 6][o % 6] = wsrc[o];
  float Aacc[6] = {0, 0, 0, 0, 0, 0};
  float Sacc[6] = {0, 0, 0, 0, 0, 0};
  int tloc = tid >> 2, q = tid & 3;
  __syncthreads();
  // commit tile 0 to LDS
#pragma unroll
  for (int k = 0; k < 5; k++) {
    int i = tid + k * 256, row = i / 20, c8 = i % 20;
    *(uint4*)&xln[row][c8 * 8] = pf[k];
  }
  __syncthreads();

#define BODY2(T, HASNEXT)                                                            \
  {                                                                                  \
    if (HASNEXT) {                                                                   \
      const unsigned short* s2 = src0 + (size_t)((T) + 1) * 64 * DD;                 \
      _Pragma("unroll") for (int k = 0; k < 5; k++) {                                \
        int i = tid + k * 256, row = i / 20, c8 = i % 20;                            \
        pf[k] = *(const uint4*)(s2 + (size_t)row * DD + c8 * 8);                     \
      }                                                                              \
    }                                                                                \
    float l0 = 0.f, l1 = 0.f, l2 = 0.f, l3 = 0.f, l4 = 0.f, l5 = 0.f;                \
    const unsigned short* xr = &xln[tloc][q * 40];                                   \
    _Pragma("unroll") for (int u = 0; u < 5; u++) {                                  \
      uint4 w = *(const uint4*)(xr + u * 8);                                         \
      unsigned int ws[4] = {w.x, w.y, w.z, w.w};                                     \
      _Pragma("unroll") for (int p2 = 0; p2 < 4; p2++) {                             \
        float f0 = u2f_lo(ws[p2]), f1 = u2f_hi(ws[p2]);                              \
        int c_ = q * 40 + u * 8 + p2 * 2;                                            \
        float2 wa = *(const float2*)&wkq_s[c_][0];                                   \
        float2 wb = *(const float2*)&wkq_s[c_][2];                                   \
        float2 wc = *(const float2*)&wkq_s[c_][4];                                   \
        l0 = fmaf(f0, wa.x, l0); l1 = fmaf(f0, wa.y, l1);                            \
        l2 = fmaf(f0, wb.x, l2); l3 = fmaf(f0, wb.y, l3);                            \
        l4 = fmaf(f0, wc.x, l4); l5 = fmaf(f0, wc.y, l5);                            \
        float2 va = *(const float2*)&wkq_s[c_ + 1][0];                               \
        float2 vb = *(const float2*)&wkq_s[c_ + 1][2];                               \
        float2 vc = *(const float2*)&wkq_s[c_ + 1][4];                               \
        l0 = fmaf(f1, va.x, l0); l1 = fmaf(f1, va.y, l1);                            \
        l2 = fmaf(f1, vb.x, l2); l3 = fmaf(f1, vb.y, l3);                            \
        l4 = fmaf(f1, vc.x, l4); l5 = fmaf(f1, vc.y, l5);                            \
      }                                                                              \
    }                                                                                \
    l0 += __shfl_xor(l0, 1); l1 += __shfl_xor(l1, 1); l2 += __shfl_xor(l2, 1);       \
    l3 += __shfl_xor(l3, 1); l4 += __shfl_xor(l4, 1); l5 += __shfl_xor(l5, 1);       \
    l0 += __shfl_xor(l0, 2); l1 += __shfl_xor(l1, 2); l2 += __shfl_xor(l2, 2);       \
    l3 += __shfl_xor(l3, 2); l4 += __shfl_xor(l4, 2); l5 += __shfl_xor(l5, 2);       \
    if (q == 0) {                                                                    \
      float mx_ = fmaxf(fmaxf(fmaxf(l0, l1), fmaxf(l2, l3)), fmaxf(l4, l5));         \
      float e0 = __expf(l0 - mx_), e1 = __expf(l1 - mx_), e2 = __expf(l2 - mx_);     \
      float e3 = __expf(l3 - mx_), e4 = __expf(l4 - mx_), e5 = __expf(l5 - mx_);     \
      float inv_ = 1.0f / (e0 + e1 + e2 + e3 + e4 + e5);                             \
      e0 *= inv_; e1 *= inv_; e2 *= inv_; e3 *= inv_; e4 *= inv_; e5 *= inv_;        \
      *(float4*)&att[tloc][0] = make_float4(e0, e1, e2, e3);                         \
      *(float2*)&att[tloc][4] = make_float2(e4, e5);                                 \
      Sacc[0] += e0; Sacc[1] += e1; Sacc[2] += e2;                                   \
      Sacc[3] += e3; Sacc[4] += e4; Sacc[5] += e5;                                   \
      size_t ob = (size_t)(n * MM) * LL + ch * (64 * NT) + (T) * 64 + tloc;          \
      attn_out[ob] = e0;          attn_out[ob + LL] = e1;                            \
      attn_out[ob + 2 * LL] = e2; attn_out[ob + 3 * LL] = e3;                        \
      attn_out[ob + 4 * LL] = e4; attn_out[ob + 5 * LL] = e5;                        \
    }                                                                                \
    __syncthreads();                                                                 \
    if (tid < DD) {                                                                  \
      _Pragma("unroll") for (int t_ = 0; t_ < 64; t_++) {                            \
        float xv = bf2f(xln[t_][tid]);                                               \
        float4 a03 = *(const float4*)&att[t_][0];                                    \
        float2 a45 = *(const float2*)&att[t_][4];                                    \
        Aacc[0] = fmaf(a03.x, xv, Aacc[0]); Aacc[1] = fmaf(a03.y, xv, Aacc[1]);      \
        Aacc[2] = fmaf(a03.z, xv, Aacc[2]); Aacc[3] = fmaf(a03.w, xv, Aacc[3]);      \
        Aacc[4] = fmaf(a45.x, xv, Aacc[4]); Aacc[5] = fmaf(a45.y, xv, Aacc[5]);      \
      }                                                                              \
    }                                                                                \
    if (HASNEXT) {                                                                   \
      __syncthreads();                                                               \
      _Pragma("unroll") for (int k = 0; k < 5; k++) {                                \
        int i = tid + k * 256, row = i / 20, c8 = i % 20;                            \
        *(uint4*)&xln[row][c8 * 8] = pf[k];                                          \
      }                                                                              \
      __syncthreads();                                                               \
    }                                                                                \
  }

  BODY2(0, true);
  BODY2(1, true);
  BODY2(2, true);
  BODY2(3, false);
#undef BODY2

  __syncthreads();
  if (tid < DD) {
#pragma unroll
    for (int m = 0; m < 6; m++) Apart[((size_t)b * 6 + m) * DD + tid] = Aacc[m];
  }
  if (q == 0) {
#pragma unroll
    for (int m = 0; m < 6; m++) sred[tloc][m] = Sacc[m];
  }
  __syncthreads();
  if (tid < 6) {
    float s = 0.f;
    for (int t = 0; t < 64; t++) s += sred[t][tid];
    Spart[b * 6 + tid] = s;
  }
}

// ---------------- k_slot2: fused per-n slot update, 512 threads ----------------
template <bool FIRST, bool LAST>
__global__ __launch_bounds__(512) void k_slot2(
    const float* slots_init, const float* Apart, const float* Spart, const float* Wv,
    const float* out_g, const float* out_b,
    const float* W1, const float* b1, const float* W2, const float* b2,
    const float* q_g, const float* q_b, const float* Wq, const float* Wk, const float* scal,
    float* slotbuf, float* Wkq2, float* Sfin, float* out_slots) {
  int n = blockIdx.x;
  int tid = threadIdx.x;
  __shared__ float a_s[MM * DD];
  __shared__ float s1[MM * DD];
  __shared__ float h[MM * 320];
  __shared__ float Sv[MM], mu_s[MM], rs_s[MM];

  if (tid < MM) {
    float s = 0.f;
#pragma unroll
    for (int p = 0; p < NCH; p++) s += Spart[(n * NCH + p) * 6 + tid];
    float sc = fmaxf(s, 1e-6f);
    Sv[tid] = sc;
    if (LAST) Sfin[n * 6 + tid] = sc;
  }
  for (int o = tid; o < MM * DD; o += 512) {
    float s = 0.f;
#pragma unroll
    for (int p = 0; p < NCH; p++) s += Apart[(size_t)n * (NCH * MM * DD) + p * (MM * DD) + o];
    a_s[o] = s;
  }
  __syncthreads();
  for (int o = tid; o < MM * DD; o += 512) {
    int m = o / DD, d = o % DD;
    float u = 0.f;
#pragma unroll 8
    for (int c = 0; c < DD; c++) u += a_s[m * DD + c] * Wv[c * DD + d];
    float prev = FIRST ? slots_init[o] : slotbuf[(size_t)n * MM * DD + o];
    s1[o] = prev + u / Sv[m];
  }
  __syncthreads();
  if (tid < 384) {
    int m = tid >> 6, l = tid & 63;
    const float* row = &s1[m * DD];
    float x0 = row[l], x1 = row[l + 64], x2 = (l < 32 ? row[l + 128] : 0.f);
    float s = x0 + x1 + x2, ss = x0 * x0 + x1 * x1 + x2 * x2;
#pragma unroll
    for (int off = 32; off >= 1; off >>= 1) { s += __shfl_xor(s, off); ss += __shfl_xor(ss, off); }
    if (l == 0) {
      float mu = s / DD, var = ss / DD - mu * mu;
      mu_s[m] = mu; rs_s[m] = rsqrtf(var + 1e-5f);
    }
  }
  __syncthreads();
  for (int o = tid; o < MM * DD; o += 512) {
    int m = o / DD, d = o % DD;
    s1[o] = (s1[o] - mu_s[m]) * rs_s[m] * out_g[d] + out_b[d];
  }
  __syncthreads();
  for (int o = tid; o < MM * 320; o += 512) {
    int m = o / 320, j = o % 320;
    float acc = b1[j];
#pragma unroll 8
    for (int d = 0; d < DD; d++) acc += s1[m * DD + d] * W1[d * 320 + j];
    h[o] = 0.5f * acc * (1.0f + erff(acc * 0.70710678118f));
  }
  __syncthreads();
  for (int o = tid; o < MM * DD; o += 512) {
    int m = o / DD, d = o % DD;
    float acc = b2[d];
#pragma unroll 8
    for (int j = 0; j < 320; j++) acc += h[m * 320 + j] * W2[j * DD + d];
    float val = s1[o] + acc;
    a_s[o] = val;
    if (LAST) out_slots[(size_t)n * MM * DD + o] = val;
    else slotbuf[(size_t)n * MM * DD + o] = val;
  }
  if (!LAST) {
    __syncthreads();
    if (tid < 384) {
      int m = tid >> 6, l = tid & 63;
      const float* row = &a_s[m * DD];
      float x0 = row[l], x1 = row[l + 64], x2 = (l < 32 ? row[l + 128] : 0.f);
      float s = x0 + x1 + x2, ss = x0 * x0 + x1 * x1 + x2 * x2;
#pragma unroll
      for (int off = 32; off >= 1; off >>= 1) { s += __shfl_xor(s, off); ss += __shfl_xor(ss, off); }
      if (l == 0) {
        float mu = s / DD, var = ss / DD - mu * mu;
        mu_s[m] = mu; rs_s[m] = rsqrtf(var + 1e-5f);
      }
    }
    __syncthreads();
    for (int o = tid; o < MM * DD; o += 512) {
      int m = o / DD, d = o % DD;
      s1[o] = (a_s[o] - mu_s[m]) * rs_s[m] * q_g[d] + q_b[d];
    }
    __syncthreads();
    for (int o = tid; o < MM * DD; o += 512) {
      int m = o / DD, d = o % DD;
      float acc = 0.f;
#pragma unroll 8
      for (int i = 0; i < DD; i++) acc += s1[m * DD + i] * Wq[i * DD + d];
      h[o] = acc;
    }
    __syncthreads();
    if (tid < DD) {
      int c = tid;
      float acc[MM] = {0, 0, 0, 0, 0, 0};
#pragma unroll 4
      for (int d = 0; d < DD; d++) {
        float wk = Wk[c * DD + d];
#pragma unroll
        for (int m = 0; m < MM; m++) acc[m] += wk * h[m * DD + d];
      }
      float sc = scal[0];
#pragma unroll
      for (int m = 0; m < MM; m++) Wkq2[(size_t)n * DD * 6 + c * 6 + m] = sc * acc[m];
    }
  }
}

// ---------------- k_norm: attn_map = attn / Sfin ----------------
__global__ __launch_bounds__(256) void k_norm(float* attn, const float* Sfin) {
  int idx = blockIdx.x * 256 + threadIdx.x;
  size_t base = (size_t)idx * 4;
  int nm = (int)(base >> 12);
  float s = Sfin[nm];
  float4 v = *(float4*)(attn + base);
  float inv = 1.0f / s;
  v.x *= inv; v.y *= inv; v.z *= inv; v.w *= inv;
  *(float4*)(attn + base) = v;
}

extern "C" void kernel_launch(void* const* d_in, const int* in_sizes, int n_in,
                              void* d_out, int out_size, void* d_ws, size_t ws_size,
                              hipStream_t stream) {
  const float* feat       = (const float*)d_in[0];
  const float* slots_init = (const float*)d_in[1];
  const float* log_tau    = (const float*)d_in[2];
  const float* kv_g       = (const float*)d_in[3];
  const float* kv_b       = (const float*)d_in[4];
  const float* Wk         = (const float*)d_in[5];
  const float* Wv         = (const float*)d_in[6];
  const float* q_g        = (const float*)d_in[7];
  const float* q_b        = (const float*)d_in[8];
  const float* Wq         = (const float*)d_in[9];
  const float* out_g      = (const float*)d_in[10];
  const float* out_b      = (const float*)d_in[11];
  const float* W1         = (const float*)d_in[12];
  const float* b1         = (const float*)d_in[13];
  const float* W2         = (const float*)d_in[14];
  const float* b2         = (const float*)d_in[15];
  float* out = (float*)d_out;
  float* out_attn = out + NN * MM * DD;

  unsigned short* xcache = (unsigned short*)d_ws;          // [64][4096][160] bf16
  float* Wkq1    = (float*)(xcache + (size_t)NN * LL * DD);// [160][6]
  float* Wkq2    = Wkq1 + DD * 6;                          // [64][160][6]
  float* P1      = Wkq2 + (size_t)NN * DD * 6;             // [160][6]
  float* ab      = P1 + DD * 6;                            // [12]
  float* Apart   = ab + 16;                                // [1024][6][160]
  float* Spart   = Apart + (size_t)NN * NCH * MM * DD;     // [1024][6]
  float* Sfin    = Spart + (size_t)NN * NCH * MM;          // [64][6]
  float* scal    = Sfin + NN * MM;                         // [1]
  float* slotbuf = scal + 8;                               // [64][6][160]
  size_t required = (size_t)((char*)(slotbuf + NN * MM * DD) - (char*)d_ws);
  if (ws_size < required) return;

  k_init<<<16, 256, 0, stream>>>(log_tau, slots_init, q_g, q_b, Wq, Wk, Wkq1, scal);
  k_init2<<<1, 256, 0, stream>>>(Wkq1, kv_g, kv_b, P1, ab);
  k_pass1<<<NN * NCH, 256, 0, stream>>>(feat, kv_g, kv_b, P1, ab, xcache, Apart, Spart);
  k_slot2<true, false><<<NN, 512, 0, stream>>>(slots_init, Apart, Spart, Wv, out_g, out_b,
                                               W1, b1, W2, b2, q_g, q_b, Wq, Wk, scal,
                                               slotbuf, Wkq2, Sfin, out);
  k_pass2<<<NN * NCH, 256, 0, stream>>>(xcache, Wkq2, Apart, Spart, out_attn);
  k_slot2<false, true><<<NN, 512, 0, stream>>>(slots_init, Apart, Spart, Wv, out_g, out_b,
                                               W1, b1, W2, b2, q_g, q_b, Wq, Wk, scal,
                                               slotbuf, Wkq2, Sfin, out);
  k_norm<<<(NN * MM * LL) / 1024, 256, 0, stream>>>(out_attn, Sfin);
}

// Round 6
// 266.189 us; speedup vs baseline: 1.5838x; 1.5838x over previous
//
#include <hip/hip_runtime.h>
#include <math.h>

#define NN 64
#define CC 160
#define LL 4096
#define DD 160
#define MM 6
#define NCH 16      // chunks per image; chunk = 256 tokens = 4 tiles of 64
#define XSTR 68     // xb row stride in tokens (136B: b64-aligned, ~2-way banks)

__device__ __forceinline__ float bf2f(unsigned short u) {
  union { unsigned int i; float f; } v; v.i = ((unsigned int)u) << 16; return v.f;
}
__device__ __forceinline__ unsigned short f2bf(float f) {
  union { float f; unsigned int i; } v; v.f = f;
  unsigned int r = v.i + 0x7fffu + ((v.i >> 16) & 1u);
  return (unsigned short)(r >> 16);
}
__device__ __forceinline__ float u2f_lo(unsigned int w) {
  union { unsigned int i; float f; } v; v.i = w << 16; return v.f;
}
__device__ __forceinline__ float u2f_hi(unsigned int w) {
  union { unsigned int i; float f; } v; v.i = w & 0xffff0000u; return v.f;
}

// ---------------- k_init: scal = (d^-0.5 / tau); Wkq1 = scal * Wk @ q1^T ----------------
__global__ __launch_bounds__(256) void k_init(
    const float* log_tau, const float* slots_init, const float* q_g, const float* q_b,
    const float* Wq, const float* Wk, float* Wkq1, float* scal) {
  __shared__ float ln[MM * DD];
  __shared__ float qv[MM * DD];
  __shared__ float mu_s[MM], rs_s[MM];
  int tid = threadIdx.x;
  float x = log_tau[0];
  float sp = (x > 20.f) ? x : log1pf(expf(x));
  float scv = (1.0f / sqrtf((float)DD)) / (sp + 0.5f);
  if (blockIdx.x == 0 && tid == 0) scal[0] = scv;
  if (tid < MM) {
    float s = 0.f, ss = 0.f;
    for (int i = 0; i < DD; i++) { float v = slots_init[tid * DD + i]; s += v; ss += v * v; }
    float mu = s / DD, var = ss / DD - mu * mu;
    mu_s[tid] = mu; rs_s[tid] = rsqrtf(var + 1e-5f);
  }
  __syncthreads();
  for (int o = tid; o < MM * DD; o += 256) {
    int m = o / DD, d = o % DD;
    ln[o] = (slots_init[o] - mu_s[m]) * rs_s[m] * q_g[d] + q_b[d];
  }
  __syncthreads();
  for (int o = tid; o < MM * DD; o += 256) {
    int m = o / DD, d = o % DD;
    float acc = 0.f;
#pragma unroll 8
    for (int i = 0; i < DD; i++) acc += ln[m * DD + i] * Wq[i * DD + d];
    qv[o] = acc;
  }
  __syncthreads();
  for (int o = tid; o < 60; o += 256) {
    int c = blockIdx.x * 10 + o / 6, m = o % 6;
    float acc = 0.f;
#pragma unroll 8
    for (int d = 0; d < DD; d++) acc += Wk[c * DD + d] * qv[m * DD + d];
    Wkq1[c * 6 + m] = scv * acc;
  }
}

// ---------------- k_init2: P1 = g .* Wkq1; ab = [alpha(=sum P1) | beta(=sum b*Wkq1)] ----------------
__global__ __launch_bounds__(256) void k_init2(
    const float* Wkq1, const float* kv_g, const float* kv_b, float* P1, float* ab) {
  int tid = threadIdx.x;
  for (int o = tid; o < DD * 6; o += 256) {
    int c = o / 6;
    P1[o] = kv_g[c] * Wkq1[o];
  }
  __syncthreads();
  if (tid < 12) {
    int m = tid % 6;
    float s = 0.f;
    if (tid < 6) { for (int c = 0; c < DD; c++) s += P1[c * 6 + m]; }
    else         { for (int c = 0; c < DD; c++) s += kv_b[c] * Wkq1[c * 6 + m]; }
    ab[tid] = s;
  }
}

// ---------------- k_pass: float4 loads, fused raw-x stats+logits, softmax, raw-x A-accum ----------------
// logits[t,m] = rs_t * (x_t . P[:,m]) - rs_t*mu_t*alpha[m] + beta[m],  P = g .* Wkq
// A_raw[m,c]  = sum_t (att*rs)[t,m] * x[t,c]   (g,b correction applied in k_slot2)
template <bool ITER2>
__global__ __launch_bounds__(256, 3) void k_pass(
    const float* __restrict__ feat, const float* __restrict__ Pg,
    const float* __restrict__ abg, float* __restrict__ Apart,
    float* __restrict__ SWpart, float* __restrict__ attn_out) {
  int b = blockIdx.x;
  int n = b >> 4, ch = b & 15;
  int tid = threadIdx.x;
  int lane = tid & 63, g = tid >> 6;
  int cg = lane >> 4, tl = lane & 15;

  __shared__ __align__(16) unsigned short xb[160 * XSTR];  // raw x, bf16, [c][token]
  __shared__ float part[4][16][4][9];                      // per-wave partials (9: conflict-free)
  __shared__ __align__(16) float w_s[64][8];               // w = att*rs per token
  __shared__ __align__(16) float P_s[160][8];
  float* sred = (float*)part;                              // [64][12] alias (used after last tile)

  const float* wsrc = ITER2 ? (Pg + (size_t)n * DD * 6) : Pg;
  for (int o = tid; o < DD * 6; o += 256) P_s[o / 6][o % 6] = wsrc[o];
  const float* absrc = ITER2 ? (abg + n * 12) : abg;
  float alpha[6], beta[6];
#pragma unroll
  for (int m = 0; m < 6; m++) { alpha[m] = absrc[m]; beta[m] = absrc[6 + m]; }
  float Aacc[6] = {0, 0, 0, 0, 0, 0};
  float Sacc[6] = {0, 0, 0, 0, 0, 0};
  float W2acc[6] = {0, 0, 0, 0, 0, 0};
  __syncthreads();

  const float* fb0 = feat + ((size_t)(n * CC + g * 40 + cg)) * LL + ch * 256 + 4 * tl;

  for (int t4 = 0; t4 < 4; t4++) {
    const float* fb = fb0 + t4 * 64;
    float s4[4] = {0, 0, 0, 0}, ss4[4] = {0, 0, 0, 0};
    float lgr[6][4];
#pragma unroll
    for (int m = 0; m < 6; m++) { lgr[m][0] = 0.f; lgr[m][1] = 0.f; lgr[m][2] = 0.f; lgr[m][3] = 0.f; }
    // ---- phase 0: float4 load; fused stats + logit partials; bf16 raw-x to LDS ----
#pragma unroll
    for (int r = 0; r < 10; r++) {
      int c = g * 40 + r * 4 + cg;
      float4 xv = *(const float4*)(fb + (size_t)(r * 4) * LL);
      float4 p03 = *(const float4*)&P_s[c][0];
      float2 p45 = *(const float2*)&P_s[c][4];
      float xs[4] = {xv.x, xv.y, xv.z, xv.w};
#pragma unroll
      for (int j = 0; j < 4; j++) {
        float x = xs[j];
        s4[j] += x; ss4[j] = fmaf(x, x, ss4[j]);
        lgr[0][j] = fmaf(x, p03.x, lgr[0][j]); lgr[1][j] = fmaf(x, p03.y, lgr[1][j]);
        lgr[2][j] = fmaf(x, p03.z, lgr[2][j]); lgr[3][j] = fmaf(x, p03.w, lgr[3][j]);
        lgr[4][j] = fmaf(x, p45.x, lgr[4][j]); lgr[5][j] = fmaf(x, p45.y, lgr[5][j]);
      }
      uint2 pk;
      pk.x = (unsigned int)f2bf(xv.x) | ((unsigned int)f2bf(xv.y) << 16);
      pk.y = (unsigned int)f2bf(xv.z) | ((unsigned int)f2bf(xv.w) << 16);
      *(uint2*)&xb[c * XSTR + 4 * tl] = pk;
    }
    // ---- cross-lane (channel-group) reduce: tokens 4tl..4tl+3 over wave's 40 channels ----
#pragma unroll
    for (int j = 0; j < 4; j++) {
      s4[j] += __shfl_xor(s4[j], 16);  s4[j] += __shfl_xor(s4[j], 32);
      ss4[j] += __shfl_xor(ss4[j], 16); ss4[j] += __shfl_xor(ss4[j], 32);
#pragma unroll
      for (int m = 0; m < 6; m++) {
        lgr[m][j] += __shfl_xor(lgr[m][j], 16);
        lgr[m][j] += __shfl_xor(lgr[m][j], 32);
      }
    }
    if (cg == 0) {
#pragma unroll
      for (int j = 0; j < 4; j++) {
        part[g][tl][j][0] = s4[j];
        part[g][tl][j][1] = ss4[j];
#pragma unroll
        for (int m = 0; m < 6; m++) part[g][tl][j][2 + m] = lgr[m][j];
      }
    }
    __syncthreads();
    // ---- phase 1: per-token combine + softmax (tid<64) ----
    if (tid < 64) {
      int tg = tid >> 2, tj = tid & 3;
      float S = 0.f, SS = 0.f, L[6] = {0, 0, 0, 0, 0, 0};
#pragma unroll
      for (int g2 = 0; g2 < 4; g2++) {
        S += part[g2][tg][tj][0];
        SS += part[g2][tg][tj][1];
#pragma unroll
        for (int m = 0; m < 6; m++) L[m] += part[g2][tg][tj][2 + m];
      }
      float mu = S * (1.0f / CC);
      float var = SS * (1.0f / CC) - mu * mu;
      float rs = rsqrtf(var + 1e-5f);
      float lg[6];
#pragma unroll
      for (int m = 0; m < 6; m++) lg[m] = rs * L[m] - rs * mu * alpha[m] + beta[m];
      float mx = lg[0];
#pragma unroll
      for (int m = 1; m < 6; m++) mx = fmaxf(mx, lg[m]);
      float e[6], sum = 0.f;
#pragma unroll
      for (int m = 0; m < 6; m++) { e[m] = __expf(lg[m] - mx); sum += e[m]; }
      float inv = 1.0f / sum;
      float att[6], wv[6];
#pragma unroll
      for (int m = 0; m < 6; m++) {
        att[m] = e[m] * inv;
        Sacc[m] += att[m];
        wv[m] = att[m] * rs;
        W2acc[m] = fmaf(wv[m], mu, W2acc[m]);
      }
      *(float4*)&w_s[tid][0] = make_float4(wv[0], wv[1], wv[2], wv[3]);
      *(float2*)&w_s[tid][4] = make_float2(wv[4], wv[5]);
      if (ITER2) {
        size_t ob = ((size_t)(n * MM)) * LL + ch * 256 + t4 * 64 + tid;
#pragma unroll
        for (int m = 0; m < 6; m++) attn_out[ob + (size_t)m * LL] = att[m];
      }
    }
    __syncthreads();
    // ---- phase 2: A_raw accumulation (tid<160 = channel c) ----
    if (tid < DD) {
      const unsigned short* xr = &xb[tid * XSTR];
#pragma unroll
      for (int k = 0; k < 16; k++) {
        uint2 xw = *(const uint2*)(xr + 4 * k);
        float xf[4] = {u2f_lo(xw.x), u2f_hi(xw.x), u2f_lo(xw.y), u2f_hi(xw.y)};
#pragma unroll
        for (int j = 0; j < 4; j++) {
          int t = 4 * k + j;
          float4 w03 = *(const float4*)&w_s[t][0];
          float2 w45 = *(const float2*)&w_s[t][4];
          float x = xf[j];
          Aacc[0] = fmaf(w03.x, x, Aacc[0]); Aacc[1] = fmaf(w03.y, x, Aacc[1]);
          Aacc[2] = fmaf(w03.z, x, Aacc[2]); Aacc[3] = fmaf(w03.w, x, Aacc[3]);
          Aacc[4] = fmaf(w45.x, x, Aacc[4]); Aacc[5] = fmaf(w45.y, x, Aacc[5]);
        }
      }
    }
    __syncthreads();
  }
  // ---- finals ----
  if (tid < DD) {
#pragma unroll
    for (int m = 0; m < 6; m++) Apart[((size_t)b * 6 + m) * DD + tid] = Aacc[m];
  }
  if (tid < 64) {
#pragma unroll
    for (int m = 0; m < 6; m++) { sred[tid * 12 + m] = Sacc[m]; sred[tid * 12 + 6 + m] = W2acc[m]; }
  }
  __syncthreads();
  if (tid < 12) {
    float s = 0.f;
    for (int t = 0; t < 64; t++) s += sred[t * 12 + tid];
    SWpart[b * 12 + tid] = s;
  }
}

// ---------------- k_slot2: partial reduce + g/b correction, slot update, LN, MLP, next P ----------------
template <bool FIRST, bool LAST>
__global__ __launch_bounds__(512) void k_slot2(
    const float* slots_init, const float* Apart, const float* SWpart, const float* Wv,
    const float* out_g, const float* out_b,
    const float* W1, const float* b1, const float* W2, const float* b2,
    const float* q_g, const float* q_b, const float* Wq, const float* Wk,
    const float* kv_g, const float* kv_b, const float* scal,
    float* slotbuf, float* P2, float* ab2, float* Sfin, float* out_slots) {
  int n = blockIdx.x;
  int tid = threadIdx.x;
  __shared__ float a_s[MM * DD];
  __shared__ float s1[MM * DD];
  __shared__ float h[MM * 320];
  __shared__ float sw[12];
  __shared__ float Sv[MM], mu_s[MM], rs_s[MM];

  if (tid < 12) {
    float s = 0.f;
#pragma unroll
    for (int p = 0; p < NCH; p++) s += SWpart[(n * NCH + p) * 12 + tid];
    sw[tid] = s;
    if (tid < 6) {
      float sc = fmaxf(s, 1e-6f);
      Sv[tid] = sc;
      if (LAST) Sfin[n * 6 + tid] = sc;
    }
  }
  __syncthreads();
  // A reduce + LN-algebra correction: a_true = g*(Araw - W2) + b*S_true
  for (int o = tid; o < MM * DD; o += 512) {
    int m = o / DD, c = o % DD;
    float ar = 0.f;
#pragma unroll
    for (int p = 0; p < NCH; p++) ar += Apart[(size_t)(n * NCH + p) * (MM * DD) + o];
    a_s[o] = kv_g[c] * (ar - sw[6 + m]) + kv_b[c] * sw[m];
  }
  __syncthreads();
  // U = a_true @ Wv / Sclip; slot update
  for (int o = tid; o < MM * DD; o += 512) {
    int m = o / DD, d = o % DD;
    float u = 0.f;
#pragma unroll 8
    for (int c = 0; c < DD; c++) u += a_s[m * DD + c] * Wv[c * DD + d];
    float prev = FIRST ? slots_init[o] : slotbuf[(size_t)n * MM * DD + o];
    s1[o] = prev + u / Sv[m];
  }
  __syncthreads();
  if (tid < 384) {
    int m = tid >> 6, l = tid & 63;
    const float* row = &s1[m * DD];
    float x0 = row[l], x1 = row[l + 64], x2 = (l < 32 ? row[l + 128] : 0.f);
    float s = x0 + x1 + x2, ss = x0 * x0 + x1 * x1 + x2 * x2;
#pragma unroll
    for (int off = 32; off >= 1; off >>= 1) { s += __shfl_xor(s, off); ss += __shfl_xor(ss, off); }
    if (l == 0) {
      float mu = s / DD, var = ss / DD - mu * mu;
      mu_s[m] = mu; rs_s[m] = rsqrtf(var + 1e-5f);
    }
  }
  __syncthreads();
  for (int o = tid; o < MM * DD; o += 512) {
    int m = o / DD, d = o % DD;
    s1[o] = (s1[o] - mu_s[m]) * rs_s[m] * out_g[d] + out_b[d];
  }
  __syncthreads();
  for (int o = tid; o < MM * 320; o += 512) {
    int m = o / 320, j = o % 320;
    float acc = b1[j];
#pragma unroll 8
    for (int d = 0; d < DD; d++) acc += s1[m * DD + d] * W1[d * 320 + j];
    h[o] = 0.5f * acc * (1.0f + erff(acc * 0.70710678118f));
  }
  __syncthreads();
  for (int o = tid; o < MM * DD; o += 512) {
    int m = o / DD, d = o % DD;
    float acc = b2[d];
#pragma unroll 8
    for (int j = 0; j < 320; j++) acc += h[m * 320 + j] * W2[j * DD + d];
    float val = s1[o] + acc;
    a_s[o] = val;
    if (LAST) out_slots[(size_t)n * MM * DD + o] = val;
    else slotbuf[(size_t)n * MM * DD + o] = val;
  }
  if (!LAST) {
    __syncthreads();
    if (tid < 384) {
      int m = tid >> 6, l = tid & 63;
      const float* row = &a_s[m * DD];
      float x0 = row[l], x1 = row[l + 64], x2 = (l < 32 ? row[l + 128] : 0.f);
      float s = x0 + x1 + x2, ss = x0 * x0 + x1 * x1 + x2 * x2;
#pragma unroll
      for (int off = 32; off >= 1; off >>= 1) { s += __shfl_xor(s, off); ss += __shfl_xor(ss, off); }
      if (l == 0) {
        float mu = s / DD, var = ss / DD - mu * mu;
        mu_s[m] = mu; rs_s[m] = rsqrtf(var + 1e-5f);
      }
    }
    __syncthreads();
    for (int o = tid; o < MM * DD; o += 512) {
      int m = o / DD, d = o % DD;
      s1[o] = (a_s[o] - mu_s[m]) * rs_s[m] * q_g[d] + q_b[d];
    }
    __syncthreads();
    for (int o = tid; o < MM * DD; o += 512) {
      int m = o / DD, d = o % DD;
      float acc = 0.f;
#pragma unroll 8
      for (int i = 0; i < DD; i++) acc += s1[m * DD + i] * Wq[i * DD + d];
      h[o] = acc;
    }
    __syncthreads();
    // P2[c][m] = g[c]*scal*(Wk[c].q2[m]);  ab2 = [sum_c P2 | sum_c b*scal*Wk.q]
    if (tid < DD) {
      int c = tid;
      float acc[MM] = {0, 0, 0, 0, 0, 0};
#pragma unroll 4
      for (int d = 0; d < DD; d++) {
        float wk = Wk[c * DD + d];
#pragma unroll
        for (int m = 0; m < MM; m++) acc[m] += wk * h[m * DD + d];
      }
      float sc = scal[0];
      float gc = kv_g[c], bc = kv_b[c];
#pragma unroll
      for (int m = 0; m < MM; m++) {
        float wr = sc * acc[m];
        P2[(size_t)n * DD * 6 + c * 6 + m] = gc * wr;
        s1[c * 6 + m] = gc * wr;
        a_s[c * 6 + m] = bc * wr;
      }
    }
    __syncthreads();
    if (tid < 12) {
      int m = tid % 6;
      const float* src = (tid < 6) ? s1 : a_s;
      float s = 0.f;
      for (int c = 0; c < DD; c++) s += src[c * 6 + m];
      ab2[n * 12 + tid] = s;
    }
  }
}

// ---------------- k_norm: attn_map = attn / Sfin ----------------
__global__ __launch_bounds__(256) void k_norm(float* attn, const float* Sfin) {
  int idx = blockIdx.x * 256 + threadIdx.x;
  size_t base = (size_t)idx * 4;
  int nm = (int)(base >> 12);
  float s = Sfin[nm];
  float4 v = *(float4*)(attn + base);
  float inv = 1.0f / s;
  v.x *= inv; v.y *= inv; v.z *= inv; v.w *= inv;
  *(float4*)(attn + base) = v;
}

extern "C" void kernel_launch(void* const* d_in, const int* in_sizes, int n_in,
                              void* d_out, int out_size, void* d_ws, size_t ws_size,
                              hipStream_t stream) {
  const float* feat       = (const float*)d_in[0];
  const float* slots_init = (const float*)d_in[1];
  const float* log_tau    = (const float*)d_in[2];
  const float* kv_g       = (const float*)d_in[3];
  const float* kv_b       = (const float*)d_in[4];
  const float* Wk         = (const float*)d_in[5];
  const float* Wv         = (const float*)d_in[6];
  const float* q_g        = (const float*)d_in[7];
  const float* q_b        = (const float*)d_in[8];
  const float* Wq         = (const float*)d_in[9];
  const float* out_g      = (const float*)d_in[10];
  const float* out_b      = (const float*)d_in[11];
  const float* W1         = (const float*)d_in[12];
  const float* b1         = (const float*)d_in[13];
  const float* W2         = (const float*)d_in[14];
  const float* b2         = (const float*)d_in[15];
  float* out = (float*)d_out;
  float* out_attn = out + NN * MM * DD;

  // workspace (fp32, ~4.5 MB)
  float* Wkq1   = (float*)d_ws;                          // [160*6]
  float* ab     = Wkq1 + DD * 6;                         // [12] (pad 16)
  float* P1     = ab + 16;                               // [160*6]
  float* P2     = P1 + DD * 6;                           // [64][160*6]
  float* ab2    = P2 + (size_t)NN * DD * 6;              // [64][12]
  float* Apart  = ab2 + NN * 12;                         // [1024][6][160]
  float* SWpart = Apart + (size_t)NN * NCH * MM * DD;    // [1024][12]
  float* Sfin   = SWpart + (size_t)NN * NCH * 12;        // [64][6]
  float* scal   = Sfin + NN * MM;                        // [1] (pad 8)
  float* slotbuf = scal + 8;                             // [64][6][160]
  size_t required = (size_t)((char*)(slotbuf + NN * MM * DD) - (char*)d_ws);
  if (ws_size < required) return;

  k_init<<<16, 256, 0, stream>>>(log_tau, slots_init, q_g, q_b, Wq, Wk, Wkq1, scal);
  k_init2<<<1, 256, 0, stream>>>(Wkq1, kv_g, kv_b, P1, ab);
  k_pass<false><<<NN * NCH, 256, 0, stream>>>(feat, P1, ab, Apart, SWpart, out_attn);
  k_slot2<true, false><<<NN, 512, 0, stream>>>(slots_init, Apart, SWpart, Wv, out_g, out_b,
                                               W1, b1, W2, b2, q_g, q_b, Wq, Wk, kv_g, kv_b, scal,
                                               slotbuf, P2, ab2, Sfin, out);
  k_pass<true><<<NN * NCH, 256, 0, stream>>>(feat, P2, ab2, Apart, SWpart, out_attn);
  k_slot2<false, true><<<NN, 512, 0, stream>>>(slots_init, Apart, SWpart, Wv, out_g, out_b,
                                               W1, b1, W2, b2, q_g, q_b, Wq, Wk, kv_g, kv_b, scal,
                                               slotbuf, P2, ab2, Sfin, out);
  k_norm<<<(NN * MM * LL) / 1024, 256, 0, stream>>>(out_attn, Sfin);
}